// Round 3
// baseline (474.414 us; speedup 1.0000x reference)
//
#include <hip/hip_runtime.h>
#include <math.h>

#define B_SZ 128
#define N_OTH 2048
#define F_IMG 1024
#define F_TXT 512
#define D_EMB 512

typedef __attribute__((ext_vector_type(8))) short short8;    // 8 bf16 (4 VGPR)
typedef __attribute__((ext_vector_type(16))) float f32x16;   // 32x32 MFMA acc

static __device__ __forceinline__ ushort f2bf(float f) {
    union { float f; unsigned u; } v; v.f = f;
    unsigned u = v.u;
    return (ushort)((u + 0x7fffu + ((u >> 16) & 1u)) >> 16);  // RNE
}

// ---------------- image encoder: img = normalize(in_img @ W_img) ----------------
__global__ __launch_bounds__(512) void k_img(const float* __restrict__ in_img,
                                             const float* __restrict__ W,
                                             float* __restrict__ img) {
    const int b = blockIdx.x;
    const int d = threadIdx.x;
    __shared__ float row[F_IMG];
    __shared__ float wsum[8];
    __shared__ float s_rn;
    for (int i = d; i < F_IMG; i += 512) row[i] = in_img[b * F_IMG + i];
    __syncthreads();
    float acc = 0.f;
#pragma unroll 8
    for (int f = 0; f < F_IMG; ++f) acc = fmaf(row[f], W[f * D_EMB + d], acc);
    float sq = acc * acc;
#pragma unroll
    for (int off = 32; off > 0; off >>= 1) sq += __shfl_down(sq, off);
    const int lane = d & 63, wv = d >> 6;
    if (lane == 0) wsum[wv] = sq;
    __syncthreads();
    if (d == 0) {
        float s = 0.f;
        for (int w = 0; w < 8; ++w) s += wsum[w];
        s_rn = 1.0f / sqrtf(s);
    }
    __syncthreads();
    img[b * D_EMB + d] = acc * s_rn;
}

// ---------------- text encoder + positive logit ----------------
__global__ __launch_bounds__(512) void k_txt(const float* __restrict__ in_txt,
                                             const float* __restrict__ W,
                                             const float* __restrict__ img,
                                             const float* __restrict__ p_ls,
                                             float* __restrict__ logit_in) {
    const int b = blockIdx.x;
    const int d = threadIdx.x;
    __shared__ float row[F_TXT];
    __shared__ float wsum[8];
    __shared__ float s_rn;
    row[d] = in_txt[b * F_TXT + d];
    __syncthreads();
    float acc = 0.f;
#pragma unroll 8
    for (int f = 0; f < F_TXT; ++f) acc = fmaf(row[f], W[f * D_EMB + d], acc);
    float sq = acc * acc;
#pragma unroll
    for (int off = 32; off > 0; off >>= 1) sq += __shfl_down(sq, off);
    const int lane = d & 63, wv = d >> 6;
    if (lane == 0) wsum[wv] = sq;
    __syncthreads();
    if (d == 0) {
        float s = 0.f;
        for (int w = 0; w < 8; ++w) s += wsum[w];
        s_rn = 1.0f / sqrtf(s);
    }
    __syncthreads();
    const float t = acc * s_rn;
    float pd = t * img[b * D_EMB + d];
#pragma unroll
    for (int off = 32; off > 0; off >>= 1) pd += __shfl_down(pd, off);
    __syncthreads();
    if (lane == 0) wsum[wv] = pd;
    __syncthreads();
    if (d == 0) {
        float s = 0.f;
        for (int w = 0; w < 8; ++w) s += wsum[w];
        logit_in[b] = expf(p_ls[0]) * s;
    }
}

// ---------------- W_txt -> bf16 in 32x32x16 MFMA B-fragment order ----------------
// frag = kstep(0..31) * 16 + ct(0..15); lane l holds col ct*32+(l&31),
// k = kstep*16 + (l>>5)*8 + j   (j = 0..7)
__global__ __launch_bounds__(256) void k_wprep(const float* __restrict__ W,
                                               ushort* __restrict__ wf) {
    const int g = blockIdx.x * 256 + threadIdx.x;   // 32768 threads
    const int l = g & 63;
    const int frag = g >> 6;
    const int kstep = frag >> 4;
    const int ct = frag & 15;
    const int col = ct * 32 + (l & 31);
    const int kb = kstep * 16 + (l >> 5) * 8;
    short8 o;
#pragma unroll
    for (int j = 0; j < 8; ++j) o[j] = (short)f2bf(W[(kb + j) * D_EMB + col]);
    *(short8*)(wf + (size_t)g * 8) = o;
}

// ---------------- fused GEMM + num/den reduction ----------------
// Block: 128 rows x 512 cols, 8 waves (each 128 rows x 64 cols), BK=64, K=512.
__global__ __launch_bounds__(512, 2) void k_gemm(const float* __restrict__ oth,
                                                 const ushort* __restrict__ wf,
                                                 const float* __restrict__ img,
                                                 float* __restrict__ numA,
                                                 float* __restrict__ denA) {
    __shared__ ushort sA[2][128 * 64];   // 2 x 16 KB, XOR-swizzled
    __shared__ float redN[8][128];
    __shared__ float redD[8][128];
    const int tid = threadIdx.x;
    const int l = tid & 63;
    const int wv = tid >> 6;
    const int b = blockIdx.x >> 4;                 // 16 blocks per batch element
    const size_t row0 = (size_t)blockIdx.x * 128;

    // staging map: thread -> 4 rows (srow + 32i), one 16B chunk each
    const int srow = tid >> 4;          // 0..31
    const int sc = tid & 15;            // 16B chunk within 64-k (256B) row-tile
    const float* gbase = oth + row0 * F_TXT;

    f32x16 acc[4][2];
#pragma unroll
    for (int m = 0; m < 4; ++m)
#pragma unroll
        for (int n = 0; n < 2; ++n)
#pragma unroll
            for (int r = 0; r < 16; ++r) acc[m][n][r] = 0.f;

    float4 nv[4];
    // prologue: stage K-tile 0
#pragma unroll
    for (int i = 0; i < 4; ++i)
        nv[i] = *(const float4*)(gbase + (size_t)(srow + i * 32) * F_TXT + sc * 4);
#pragma unroll
    for (int i = 0; i < 4; ++i) {
        const int r = srow + i * 32;
        ushort4 p;
        p.x = f2bf(nv[i].x); p.y = f2bf(nv[i].y); p.z = f2bf(nv[i].z); p.w = f2bf(nv[i].w);
        *(ushort4*)((char*)sA[0] + r * 128 + ((sc * 8) ^ ((r & 7) << 4))) = p;
    }

    for (int t = 0; t < 8; ++t) {
        const int cur = t & 1;
        __syncthreads();
        // issue next-tile global loads early (in flight under the MFMAs)
        if (t < 7) {
#pragma unroll
            for (int i = 0; i < 4; ++i)
                nv[i] = *(const float4*)(gbase + (size_t)(srow + i * 32) * F_TXT + (t + 1) * 64 + sc * 4);
        }
        // B fragments for this K-tile (L2-resident)
        short8 bfr[4][2];
#pragma unroll
        for (int ks = 0; ks < 4; ++ks)
#pragma unroll
            for (int n = 0; n < 2; ++n)
                bfr[ks][n] = *(const short8*)(wf + (((size_t)((t * 4 + ks) * 16 + wv * 2 + n)) * 64 + l) * 8);
#pragma unroll
        for (int ks = 0; ks < 4; ++ks) {
            short8 af[4];
#pragma unroll
            for (int m = 0; m < 4; ++m) {
                const int r = m * 32 + (l & 31);
                af[m] = *(const short8*)((const char*)sA[cur] + r * 128 +
                                         ((ks * 32 + (l >> 5) * 16) ^ ((r & 7) << 4)));
            }
#pragma unroll
            for (int m = 0; m < 4; ++m)
#pragma unroll
                for (int n = 0; n < 2; ++n)
                    acc[m][n] = __builtin_amdgcn_mfma_f32_32x32x16_bf16(af[m], bfr[ks][n], acc[m][n], 0, 0, 0);
        }
        // convert + write next tile into the other buffer
        if (t < 7) {
#pragma unroll
            for (int i = 0; i < 4; ++i) {
                const int r = srow + i * 32;
                ushort4 p;
                p.x = f2bf(nv[i].x); p.y = f2bf(nv[i].y); p.z = f2bf(nv[i].z); p.w = f2bf(nv[i].w);
                *(ushort4*)((char*)sA[cur ^ 1] + r * 128 + ((sc * 8) ^ ((r & 7) << 4))) = p;
            }
        }
    }

    // epilogue: per-row num = sum_c P*img[c], den = sum_c P^2
    const float ic0 = img[b * D_EMB + wv * 64 + (l & 31)];
    const float ic1 = img[b * D_EMB + wv * 64 + 32 + (l & 31)];
#pragma unroll
    for (int m = 0; m < 4; ++m) {
#pragma unroll
        for (int rg = 0; rg < 16; ++rg) {
            const float p = acc[m][0][rg];
            const float q = acc[m][1][rg];
            float tn = p * ic0 + q * ic1;
            float td = p * p + q * q;
#pragma unroll
            for (int off = 1; off <= 16; off <<= 1) {
                tn += __shfl_xor(tn, off);
                td += __shfl_xor(td, off);
            }
            if ((l & 31) == 0) {
                const int r = m * 32 + (rg & 3) + 8 * (rg >> 2) + 4 * (l >> 5);
                redN[wv][r] = tn;
                redD[wv][r] = td;
            }
        }
    }
    __syncthreads();
    if (tid < 128) {
        float tn = 0.f, td = 0.f;
#pragma unroll
        for (int w = 0; w < 8; ++w) { tn += redN[w][tid]; td += redD[w][tid]; }
        numA[row0 + tid] = tn;
        denA[row0 + tid] = td;
    }
}

// ---------------- logits + full bitonic sort + output assembly ----------------
__global__ __launch_bounds__(256) void k_topk(const float* __restrict__ numA,
                                              const float* __restrict__ denA,
                                              const float* __restrict__ logit_in,
                                              const float* __restrict__ p_ls,
                                              float* __restrict__ out) {
    const int b = blockIdx.x;
    const int tid = threadIdx.x;
    const float scale = expf(p_ls[0]);
    __shared__ float a[N_OTH];
    for (int i = tid; i < N_OTH; i += 256) {
        const float nu = numA[(size_t)b * N_OTH + i];
        const float de = denA[(size_t)b * N_OTH + i];
        a[i] = scale * nu / sqrtf(de);
    }
    __syncthreads();
    for (unsigned k = 2; k <= N_OTH; k <<= 1) {
        for (unsigned j = k >> 1; j > 0; j >>= 1) {
            for (int s = 0; s < N_OTH / 256; ++s) {
                const unsigned i = tid + s * 256u;
                const unsigned ixj = i ^ j;
                if (ixj > i) {
                    const bool asc = ((i & k) == 0);
                    const float x = a[i], y = a[ixj];
                    if ((x > y) == asc) { a[i] = y; a[ixj] = x; }
                }
            }
            __syncthreads();
        }
    }
    if (tid < 128) {
        const int j = tid;
        float v;
        if (j == b) {
            v = logit_in[b];
        } else {
            const int m = j - (j > b ? 1 : 0);
            v = a[N_OTH - 1 - m];
        }
        out[b * 128 + j] = v;
    }
}

extern "C" void kernel_launch(void* const* d_in, const int* in_sizes, int n_in,
                              void* d_out, int out_size, void* d_ws, size_t ws_size,
                              hipStream_t stream) {
    const float* in_img = (const float*)d_in[0];
    const float* in_txt = (const float*)d_in[1];
    const float* oth    = (const float*)d_in[2];
    const float* W_img  = (const float*)d_in[3];
    const float* W_txt  = (const float*)d_in[4];
    const float* p_ls   = (const float*)d_in[5];
    float* out = (float*)d_out;

    float* ws = (float*)d_ws;
    float* img      = ws;                                  // 65536 floats
    float* logit_in = ws + 65536;                          // 128
    float* numA     = ws + 65536 + 128;                    // 262144
    float* denA     = numA + 262144;                       // 262144
    ushort* wfrag   = (ushort*)(denA + 262144);            // 262144 ushorts (512 KB)

    k_wprep<<<128, 256, 0, stream>>>(W_txt, wfrag);
    k_img<<<B_SZ, 512, 0, stream>>>(in_img, W_img, img);
    k_txt<<<B_SZ, 512, 0, stream>>>(in_txt, W_txt, img, p_ls, logit_in);
    k_gemm<<<(B_SZ * N_OTH) / 128, 512, 0, stream>>>(oth, wfrag, img, numA, denA);
    k_topk<<<B_SZ, 256, 0, stream>>>(numA, denA, logit_in, p_ls, out);
}

// Round 5
// 426.171 us; speedup vs baseline: 1.1132x; 1.1132x over previous
//
#include <hip/hip_runtime.h>
#include <hip/hip_bf16.h>
#include <math.h>

#define B_SZ 128
#define N_OTH 2048
#define F_IMG 1024
#define F_TXT 512
#define D_EMB 512

typedef __attribute__((ext_vector_type(8))) short short8;    // 8 bf16 (4 VGPR)
typedef __attribute__((ext_vector_type(16))) float f32x16;   // 32x32 MFMA acc

static __device__ __forceinline__ ushort f2bf(float f) {
    __hip_bfloat16 h = __float2bfloat16(f);   // HW RNE convert
    return *reinterpret_cast<ushort*>(&h);
}

// ---------------- image encoder: img = normalize(in_img @ W_img) ----------------
__global__ __launch_bounds__(512) void k_img(const float* __restrict__ in_img,
                                             const float* __restrict__ W,
                                             float* __restrict__ img) {
    const int b = blockIdx.x;
    const int d = threadIdx.x;
    __shared__ float row[F_IMG];
    __shared__ float wsum[8];
    __shared__ float s_rn;
    for (int i = d; i < F_IMG; i += 512) row[i] = in_img[b * F_IMG + i];
    __syncthreads();
    float acc = 0.f;
#pragma unroll 8
    for (int f = 0; f < F_IMG; ++f) acc = fmaf(row[f], W[f * D_EMB + d], acc);
    float sq = acc * acc;
#pragma unroll
    for (int off = 32; off > 0; off >>= 1) sq += __shfl_down(sq, off);
    const int lane = d & 63, wv = d >> 6;
    if (lane == 0) wsum[wv] = sq;
    __syncthreads();
    if (d == 0) {
        float s = 0.f;
        for (int w = 0; w < 8; ++w) s += wsum[w];
        s_rn = 1.0f / sqrtf(s);
    }
    __syncthreads();
    img[b * D_EMB + d] = acc * s_rn;
}

// ---------------- text encoder + positive logit ----------------
__global__ __launch_bounds__(512) void k_txt(const float* __restrict__ in_txt,
                                             const float* __restrict__ W,
                                             const float* __restrict__ img,
                                             const float* __restrict__ p_ls,
                                             float* __restrict__ logit_in) {
    const int b = blockIdx.x;
    const int d = threadIdx.x;
    __shared__ float row[F_TXT];
    __shared__ float wsum[8];
    __shared__ float s_rn;
    row[d] = in_txt[b * F_TXT + d];
    __syncthreads();
    float acc = 0.f;
#pragma unroll 8
    for (int f = 0; f < F_TXT; ++f) acc = fmaf(row[f], W[f * D_EMB + d], acc);
    float sq = acc * acc;
#pragma unroll
    for (int off = 32; off > 0; off >>= 1) sq += __shfl_down(sq, off);
    const int lane = d & 63, wv = d >> 6;
    if (lane == 0) wsum[wv] = sq;
    __syncthreads();
    if (d == 0) {
        float s = 0.f;
        for (int w = 0; w < 8; ++w) s += wsum[w];
        s_rn = 1.0f / sqrtf(s);
    }
    __syncthreads();
    const float t = acc * s_rn;
    float pd = t * img[b * D_EMB + d];
#pragma unroll
    for (int off = 32; off > 0; off >>= 1) pd += __shfl_down(pd, off);
    __syncthreads();
    if (lane == 0) wsum[wv] = pd;
    __syncthreads();
    if (d == 0) {
        float s = 0.f;
        for (int w = 0; w < 8; ++w) s += wsum[w];
        logit_in[b] = expf(p_ls[0]) * s;
    }
}

// ---------------- W_txt -> bf16 in 32x32x16 MFMA B-fragment order ----------------
// frag = kstep(0..31) * 16 + ct(0..15); lane l holds col ct*32+(l&31),
// k = kstep*16 + (l>>5)*8 + j   (j = 0..7)
__global__ __launch_bounds__(256) void k_wprep(const float* __restrict__ W,
                                               ushort* __restrict__ wf) {
    const int g = blockIdx.x * 256 + threadIdx.x;   // 32768 threads
    const int l = g & 63;
    const int frag = g >> 6;
    const int kstep = frag >> 4;
    const int ct = frag & 15;
    const int col = ct * 32 + (l & 31);
    const int kb = kstep * 16 + (l >> 5) * 8;
    short8 o;
#pragma unroll
    for (int j = 0; j < 8; ++j) o[j] = (short)f2bf(W[(kb + j) * D_EMB + col]);
    *(short8*)(wf + (size_t)g * 8) = o;
}

// ---------------- fused GEMM + num/den reduction ----------------
// Block: 128 rows x 512 cols, 8 waves (each 128 rows x 64 cols), BK=64, K=512.
// LDS A-tile: bf16 [128 rows][64 k], row = 128 B, 16B-chunk XOR swizzle (r&7)<<4.
__global__ __launch_bounds__(512, 2) void k_gemm(const float* __restrict__ oth,
                                                 const ushort* __restrict__ wf,
                                                 const float* __restrict__ img,
                                                 float* __restrict__ numA,
                                                 float* __restrict__ denA) {
    __shared__ ushort sA[2][128 * 64];   // 2 x 16 KB bf16, swizzled
    __shared__ float redN[8][128];
    __shared__ float redD[8][128];
    const int tid = threadIdx.x;
    const int l = tid & 63;
    const int wv = tid >> 6;
    const int b = blockIdx.x >> 4;                 // 16 blocks per batch element
    const size_t row0 = (size_t)blockIdx.x * 128;

    // staging map: thread -> 1 row, 16 consecutive k (64 B global, 32 B LDS)
    const int srow = tid >> 2;           // 0..127
    const int sk0 = (tid & 3) * 16;      // k start within 64-k tile
    const float* gsrc = oth + (row0 + srow) * F_TXT + sk0;
    const int swz = (srow & 7) << 4;
    const int wb0 = srow * 128 + ((sk0 * 2 + 0) ^ swz);   // byte offsets in tile
    const int wb1 = srow * 128 + ((sk0 * 2 + 16) ^ swz);

    // B base: frag index ((t*64 + ks*16 + wv*2 + n)*64 + l)*8 ushorts
    const ushort* wbase = wf + ((size_t)(wv * 2) * 64 + l) * 8;

    // A-read addressing: row r = m*32 + (l&31); k-chunk (ks*32 + (l>>5)*16) ^ ((l&7)<<4)
    int rowbase[4];
#pragma unroll
    for (int m = 0; m < 4; ++m) rowbase[m] = (m * 32 + (l & 31)) * 128;
    int koff[4];
#pragma unroll
    for (int ks = 0; ks < 4; ++ks) koff[ks] = ((ks * 32 + (l >> 5) * 16) ^ ((l & 7) << 4));

    f32x16 acc[4][2];
#pragma unroll
    for (int m = 0; m < 4; ++m)
#pragma unroll
        for (int n = 0; n < 2; ++n)
#pragma unroll
            for (int r = 0; r < 16; ++r) acc[m][n][r] = 0.f;

    // prologue: stage K-tile 0
    {
        float4 v0 = *(const float4*)(gsrc + 0);
        float4 v1 = *(const float4*)(gsrc + 4);
        float4 v2 = *(const float4*)(gsrc + 8);
        float4 v3 = *(const float4*)(gsrc + 12);
        short8 p0, p1;
        p0[0] = (short)f2bf(v0.x); p0[1] = (short)f2bf(v0.y); p0[2] = (short)f2bf(v0.z); p0[3] = (short)f2bf(v0.w);
        p0[4] = (short)f2bf(v1.x); p0[5] = (short)f2bf(v1.y); p0[6] = (short)f2bf(v1.z); p0[7] = (short)f2bf(v1.w);
        p1[0] = (short)f2bf(v2.x); p1[1] = (short)f2bf(v2.y); p1[2] = (short)f2bf(v2.z); p1[3] = (short)f2bf(v2.w);
        p1[4] = (short)f2bf(v3.x); p1[5] = (short)f2bf(v3.y); p1[6] = (short)f2bf(v3.z); p1[7] = (short)f2bf(v3.w);
        *(short8*)((char*)sA[0] + wb0) = p0;
        *(short8*)((char*)sA[0] + wb1) = p1;
    }
    __syncthreads();

    for (int t = 0; t < 8; ++t) {
        const int cur = t & 1;
        // 1) B fragments for tile t FIRST (L2-resident; first MFMA waits only on these)
        short8 bfr[4][2];
#pragma unroll
        for (int ks = 0; ks < 4; ++ks)
#pragma unroll
            for (int n = 0; n < 2; ++n)
                bfr[ks][n] = *(const short8*)(wbase + (size_t)(t * 64 + ks * 16 + n) * 512);
        __builtin_amdgcn_sched_barrier(0);   // keep B issued before the HBM prefetch
        // 2) A-prefetch for tile t+1 (HBM; lands before use at end of this tile)
        float4 nv0, nv1, nv2, nv3;
        if (t < 7) {
            const float* gs = gsrc + (t + 1) * 64;
            nv0 = *(const float4*)(gs + 0);
            nv1 = *(const float4*)(gs + 4);
            nv2 = *(const float4*)(gs + 8);
            nv3 = *(const float4*)(gs + 12);
        }
        __builtin_amdgcn_sched_barrier(0);
        // 3) compute tile t from sA[cur]
#pragma unroll
        for (int ks = 0; ks < 4; ++ks) {
            short8 af[4];
#pragma unroll
            for (int m = 0; m < 4; ++m)
                af[m] = *(const short8*)((const char*)sA[cur] + rowbase[m] + koff[ks]);
#pragma unroll
            for (int m = 0; m < 4; ++m)
#pragma unroll
                for (int n = 0; n < 2; ++n)
                    acc[m][n] = __builtin_amdgcn_mfma_f32_32x32x16_bf16(af[m], bfr[ks][n], acc[m][n], 0, 0, 0);
        }
        // 4) convert + stage tile t+1 into the other buffer
        if (t < 7) {
            short8 p0, p1;
            p0[0] = (short)f2bf(nv0.x); p0[1] = (short)f2bf(nv0.y); p0[2] = (short)f2bf(nv0.z); p0[3] = (short)f2bf(nv0.w);
            p0[4] = (short)f2bf(nv1.x); p0[5] = (short)f2bf(nv1.y); p0[6] = (short)f2bf(nv1.z); p0[7] = (short)f2bf(nv1.w);
            p1[0] = (short)f2bf(nv2.x); p1[1] = (short)f2bf(nv2.y); p1[2] = (short)f2bf(nv2.z); p1[3] = (short)f2bf(nv2.w);
            p1[4] = (short)f2bf(nv3.x); p1[5] = (short)f2bf(nv3.y); p1[6] = (short)f2bf(nv3.z); p1[7] = (short)f2bf(nv3.w);
            *(short8*)((char*)sA[cur ^ 1] + wb0) = p0;
            *(short8*)((char*)sA[cur ^ 1] + wb1) = p1;
        }
        __syncthreads();   // tile t+1 staged + everyone done with sA[cur]
    }

    // epilogue: per-row num = sum_c P*img[c], den = sum_c P^2
    const float ic0 = img[b * D_EMB + wv * 64 + (l & 31)];
    const float ic1 = img[b * D_EMB + wv * 64 + 32 + (l & 31)];
#pragma unroll
    for (int m = 0; m < 4; ++m) {
#pragma unroll
        for (int rg = 0; rg < 16; ++rg) {
            const float p = acc[m][0][rg];
            const float q = acc[m][1][rg];
            float tn = p * ic0 + q * ic1;
            float td = p * p + q * q;
#pragma unroll
            for (int off = 1; off <= 16; off <<= 1) {
                tn += __shfl_xor(tn, off);
                td += __shfl_xor(td, off);
            }
            if ((l & 31) == 0) {
                const int r = m * 32 + (rg & 3) + 8 * (rg >> 2) + 4 * (l >> 5);
                redN[wv][r] = tn;
                redD[wv][r] = td;
            }
        }
    }
    __syncthreads();
    if (tid < 128) {
        float tn = 0.f, td = 0.f;
#pragma unroll
        for (int w = 0; w < 8; ++w) { tn += redN[w][tid]; td += redD[w][tid]; }
        numA[row0 + tid] = tn;
        denA[row0 + tid] = td;
    }
}

// ---------------- logits + full bitonic sort + output assembly ----------------
__global__ __launch_bounds__(256) void k_topk(const float* __restrict__ numA,
                                              const float* __restrict__ denA,
                                              const float* __restrict__ logit_in,
                                              const float* __restrict__ p_ls,
                                              float* __restrict__ out) {
    const int b = blockIdx.x;
    const int tid = threadIdx.x;
    const float scale = expf(p_ls[0]);
    __shared__ float a[N_OTH];
    for (int i = tid; i < N_OTH; i += 256) {
        const float nu = numA[(size_t)b * N_OTH + i];
        const float de = denA[(size_t)b * N_OTH + i];
        a[i] = scale * nu / sqrtf(de);
    }
    __syncthreads();
    for (unsigned k = 2; k <= N_OTH; k <<= 1) {
        for (unsigned j = k >> 1; j > 0; j >>= 1) {
            for (int s = 0; s < N_OTH / 256; ++s) {
                const unsigned i = tid + s * 256u;
                const unsigned ixj = i ^ j;
                if (ixj > i) {
                    const bool asc = ((i & k) == 0);
                    const float x = a[i], y = a[ixj];
                    if ((x > y) == asc) { a[i] = y; a[ixj] = x; }
                }
            }
            __syncthreads();
        }
    }
    if (tid < 128) {
        const int j = tid;
        float v;
        if (j == b) {
            v = logit_in[b];
        } else {
            const int m = j - (j > b ? 1 : 0);
            v = a[N_OTH - 1 - m];
        }
        out[b * 128 + j] = v;
    }
}

extern "C" void kernel_launch(void* const* d_in, const int* in_sizes, int n_in,
                              void* d_out, int out_size, void* d_ws, size_t ws_size,
                              hipStream_t stream) {
    const float* in_img = (const float*)d_in[0];
    const float* in_txt = (const float*)d_in[1];
    const float* oth    = (const float*)d_in[2];
    const float* W_img  = (const float*)d_in[3];
    const float* W_txt  = (const float*)d_in[4];
    const float* p_ls   = (const float*)d_in[5];
    float* out = (float*)d_out;

    float* ws = (float*)d_ws;
    float* img      = ws;                                  // 65536 floats
    float* logit_in = ws + 65536;                          // 128
    float* numA     = ws + 65536 + 128;                    // 262144
    float* denA     = numA + 262144;                       // 262144
    ushort* wfrag   = (ushort*)(denA + 262144);            // 262144 ushorts (512 KB)

    k_wprep<<<128, 256, 0, stream>>>(W_txt, wfrag);
    k_img<<<B_SZ, 512, 0, stream>>>(in_img, W_img, img);
    k_txt<<<B_SZ, 512, 0, stream>>>(in_txt, W_txt, img, p_ls, logit_in);
    k_gemm<<<(B_SZ * N_OTH) / 128, 512, 0, stream>>>(oth, wfrag, img, numA, denA);
    k_topk<<<B_SZ, 256, 0, stream>>>(numA, denA, logit_in, p_ls, out);
}

// Round 7
// 335.017 us; speedup vs baseline: 1.4161x; 1.2721x over previous
//
#include <hip/hip_runtime.h>
#include <hip/hip_bf16.h>
#include <math.h>

#define B_SZ 128
#define N_OTH 2048
#define F_IMG 1024
#define F_TXT 512
#define D_EMB 512

typedef __attribute__((ext_vector_type(8))) short short8;    // 8 bf16 (4 VGPR)
typedef __attribute__((ext_vector_type(16))) float f32x16;   // 32x32 MFMA acc

static __device__ __forceinline__ ushort f2bf(float f) {
    __hip_bfloat16 h = __float2bfloat16(f);   // HW RNE convert
    return *reinterpret_cast<ushort*>(&h);
}

// ---------------- fused encoders: img row + txt row + positive logit ----------------
__global__ __launch_bounds__(512) void k_enc(const float* __restrict__ in_img,
                                             const float* __restrict__ in_txt,
                                             const float* __restrict__ W_img,
                                             const float* __restrict__ W_txt,
                                             const float* __restrict__ p_ls,
                                             float* __restrict__ img,
                                             float* __restrict__ logit_in) {
    const int b = blockIdx.x;
    const int d = threadIdx.x;
    __shared__ float row[F_IMG];
    __shared__ float wsum[8];
    __shared__ float s_rn;
    const int lane = d & 63, wv = d >> 6;

    // ---- image ----
    for (int i = d; i < F_IMG; i += 512) row[i] = in_img[b * F_IMG + i];
    __syncthreads();
    float acc = 0.f;
#pragma unroll 8
    for (int f = 0; f < F_IMG; ++f) acc = fmaf(row[f], W_img[f * D_EMB + d], acc);
    float sq = acc * acc;
#pragma unroll
    for (int off = 32; off > 0; off >>= 1) sq += __shfl_down(sq, off);
    if (lane == 0) wsum[wv] = sq;
    __syncthreads();
    if (d == 0) {
        float s = 0.f;
        for (int w = 0; w < 8; ++w) s += wsum[w];
        s_rn = 1.0f / sqrtf(s);
    }
    __syncthreads();
    const float iv = acc * s_rn;
    img[b * D_EMB + d] = iv;

    // ---- text ----
    __syncthreads();
    row[d] = in_txt[b * F_TXT + d];
    __syncthreads();
    float tacc = 0.f;
#pragma unroll 8
    for (int f = 0; f < F_TXT; ++f) tacc = fmaf(row[f], W_txt[f * D_EMB + d], tacc);
    float tsq = tacc * tacc;
#pragma unroll
    for (int off = 32; off > 0; off >>= 1) tsq += __shfl_down(tsq, off);
    __syncthreads();
    if (lane == 0) wsum[wv] = tsq;
    __syncthreads();
    if (d == 0) {
        float s = 0.f;
        for (int w = 0; w < 8; ++w) s += wsum[w];
        s_rn = 1.0f / sqrtf(s);
    }
    __syncthreads();
    float pd = (tacc * s_rn) * iv;
#pragma unroll
    for (int off = 32; off > 0; off >>= 1) pd += __shfl_down(pd, off);
    __syncthreads();
    if (lane == 0) wsum[wv] = pd;
    __syncthreads();
    if (d == 0) {
        float s = 0.f;
        for (int w = 0; w < 8; ++w) s += wsum[w];
        logit_in[b] = expf(p_ls[0]) * s;
    }
}

// ---------------- W_txt -> bf16 in 32x32x16 MFMA B-fragment order ----------------
// frag = kstep(0..31) * 16 + ct(0..15); lane l holds col ct*32+(l&31),
// k = kstep*16 + (l>>5)*8 + j   (j = 0..7)
__global__ __launch_bounds__(256) void k_wprep(const float* __restrict__ W,
                                               ushort* __restrict__ wf) {
    const int g = blockIdx.x * 256 + threadIdx.x;   // 32768 threads
    const int l = g & 63;
    const int frag = g >> 6;
    const int kstep = frag >> 4;
    const int ct = frag & 15;
    const int col = ct * 32 + (l & 31);
    const int kb = kstep * 16 + (l >> 5) * 8;
    short8 o;
#pragma unroll
    for (int j = 0; j < 8; ++j) o[j] = (short)f2bf(W[(kb + j) * D_EMB + col]);
    *(short8*)(wf + (size_t)g * 8) = o;
}

// ---------------- fused GEMM + num/den reduction ----------------
// Block: 256 thr = 4 waves. BM=64 rows, BN=512 cols, BK=64, K=512 (8 tiles).
// Wave w: all 64 rows x cols [w*128, w*128+128). acc = 2m x 4n x f32x16 = 128.
// LDS A-tile: bf16 [64][64], row=128B, 16B-granule XOR swizzle (r&7)<<4. 2 blocks/CU.
__global__ __launch_bounds__(256, 2) void k_gemm(const float* __restrict__ oth,
                                                 const ushort* __restrict__ wf,
                                                 const float* __restrict__ img,
                                                 float* __restrict__ numA,
                                                 float* __restrict__ denA) {
    __shared__ ushort sA[2][64 * 64];   // 2 x 8 KB bf16, swizzled
    __shared__ float redN[4][64];
    __shared__ float redD[4][64];
    const int tid = threadIdx.x;
    const int l = tid & 63;
    const int wv = tid >> 6;
    const int b = blockIdx.x >> 5;                 // 32 blocks per batch element
    const size_t row0 = (size_t)blockIdx.x * 64;

    // staging map: thread -> 1 row, 16 consecutive k (64 B global, 32 B LDS)
    const int srow = tid >> 2;           // 0..63
    const int sk0 = (tid & 3) * 16;      // k start within 64-k tile
    const float* gsrc = oth + (row0 + srow) * F_TXT + sk0;
    const int swz = (srow & 7) << 4;
    const int wb0 = srow * 128 + ((sk0 * 2 + 0) ^ swz);
    const int wb1 = srow * 128 + ((sk0 * 2 + 16) ^ swz);

    // B fragments: ct = wv*4 + n; frag f = (t*4+ks)*16 + ct; addr = (f*64+l)*8 ushorts
    const ushort* wbase = wf + ((size_t)(wv * 4) * 64 + l) * 8;

    // A-read addressing: row r = m*32 + (l&31); byte = r*128 + ((ks*32+(l>>5)*16) ^ ((l&7)<<4))
    int rowbase[2];
#pragma unroll
    for (int m = 0; m < 2; ++m) rowbase[m] = (m * 32 + (l & 31)) * 128;
    int koff[4];
#pragma unroll
    for (int ks = 0; ks < 4; ++ks) koff[ks] = ((ks * 32 + (l >> 5) * 16) ^ ((l & 7) << 4));

    f32x16 acc[2][4];
#pragma unroll
    for (int m = 0; m < 2; ++m)
#pragma unroll
        for (int n = 0; n < 4; ++n)
#pragma unroll
            for (int r = 0; r < 16; ++r) acc[m][n][r] = 0.f;

    // prologue: stage K-tile 0
    {
        float4 v0 = *(const float4*)(gsrc + 0);
        float4 v1 = *(const float4*)(gsrc + 4);
        float4 v2 = *(const float4*)(gsrc + 8);
        float4 v3 = *(const float4*)(gsrc + 12);
        short8 p0, p1;
        p0[0] = (short)f2bf(v0.x); p0[1] = (short)f2bf(v0.y); p0[2] = (short)f2bf(v0.z); p0[3] = (short)f2bf(v0.w);
        p0[4] = (short)f2bf(v1.x); p0[5] = (short)f2bf(v1.y); p0[6] = (short)f2bf(v1.z); p0[7] = (short)f2bf(v1.w);
        p1[0] = (short)f2bf(v2.x); p1[1] = (short)f2bf(v2.y); p1[2] = (short)f2bf(v2.z); p1[3] = (short)f2bf(v2.w);
        p1[4] = (short)f2bf(v3.x); p1[5] = (short)f2bf(v3.y); p1[6] = (short)f2bf(v3.z); p1[7] = (short)f2bf(v3.w);
        *(short8*)((char*)sA[0] + wb0) = p0;
        *(short8*)((char*)sA[0] + wb1) = p1;
    }
    __syncthreads();

    for (int t = 0; t < 8; ++t) {
        const int cur = t & 1;
        // 1) issue ALL 16 B-fragment loads for tile t FIRST (L2-resident).
        //    vmcnt is in-order: nothing older outstanding except last tile's A (already consumed).
        short8 bfr[4][4];
#pragma unroll
        for (int ks = 0; ks < 4; ++ks)
#pragma unroll
            for (int n = 0; n < 4; ++n)
                bfr[ks][n] = *(const short8*)(wbase + (size_t)((t * 4 + ks) * 8192 + n * 512));
        __builtin_amdgcn_sched_barrier(0);
        // 2) issue the HBM A-prefetch for tile t+1 AFTER all B issues:
        //    waits on B never drain this load.
        float4 nv0, nv1, nv2, nv3;
        if (t < 7) {
            const float* gs = gsrc + (t + 1) * 64;
            nv0 = *(const float4*)(gs + 0);
            nv1 = *(const float4*)(gs + 4);
            nv2 = *(const float4*)(gs + 8);
            nv3 = *(const float4*)(gs + 12);
        }
        __builtin_amdgcn_sched_barrier(0);
        // 3) compute tile t from sA[cur]
#pragma unroll
        for (int ks = 0; ks < 4; ++ks) {
            short8 af[2];
#pragma unroll
            for (int m = 0; m < 2; ++m)
                af[m] = *(const short8*)((const char*)sA[cur] + rowbase[m] + koff[ks]);
#pragma unroll
            for (int m = 0; m < 2; ++m)
#pragma unroll
                for (int n = 0; n < 4; ++n)
                    acc[m][n] = __builtin_amdgcn_mfma_f32_32x32x16_bf16(af[m], bfr[ks][n], acc[m][n], 0, 0, 0);
        }
        // 4) convert + stage tile t+1 into the other buffer
        if (t < 7) {
            short8 p0, p1;
            p0[0] = (short)f2bf(nv0.x); p0[1] = (short)f2bf(nv0.y); p0[2] = (short)f2bf(nv0.z); p0[3] = (short)f2bf(nv0.w);
            p0[4] = (short)f2bf(nv1.x); p0[5] = (short)f2bf(nv1.y); p0[6] = (short)f2bf(nv1.z); p0[7] = (short)f2bf(nv1.w);
            p1[0] = (short)f2bf(nv2.x); p1[1] = (short)f2bf(nv2.y); p1[2] = (short)f2bf(nv2.z); p1[3] = (short)f2bf(nv2.w);
            p1[4] = (short)f2bf(nv3.x); p1[5] = (short)f2bf(nv3.y); p1[6] = (short)f2bf(nv3.z); p1[7] = (short)f2bf(nv3.w);
            *(short8*)((char*)sA[cur ^ 1] + wb0) = p0;
            *(short8*)((char*)sA[cur ^ 1] + wb1) = p1;
        }
        __syncthreads();
    }

    // epilogue: per-row num = sum_c P*img[c], den = sum_c P^2
    float ic[4];
#pragma unroll
    for (int n = 0; n < 4; ++n)
        ic[n] = img[b * D_EMB + wv * 128 + n * 32 + (l & 31)];
#pragma unroll
    for (int m = 0; m < 2; ++m) {
#pragma unroll
        for (int rg = 0; rg < 16; ++rg) {
            float tn = 0.f, td = 0.f;
#pragma unroll
            for (int n = 0; n < 4; ++n) {
                const float p = acc[m][n][rg];
                tn = fmaf(p, ic[n], tn);
                td = fmaf(p, p, td);
            }
#pragma unroll
            for (int off = 1; off <= 16; off <<= 1) {
                tn += __shfl_xor(tn, off);
                td += __shfl_xor(td, off);
            }
            if ((l & 31) == 0) {
                const int r = m * 32 + (rg & 3) + 8 * (rg >> 2) + 4 * (l >> 5);
                redN[wv][r] = tn;
                redD[wv][r] = td;
            }
        }
    }
    __syncthreads();
    if (tid < 64) {
        float tn = 0.f, td = 0.f;
#pragma unroll
        for (int w = 0; w < 4; ++w) { tn += redN[w][tid]; td += redD[w][tid]; }
        numA[row0 + tid] = tn;
        denA[row0 + tid] = td;
    }
}

// ---------------- logits + full bitonic sort + output assembly ----------------
__global__ __launch_bounds__(512) void k_topk(const float* __restrict__ numA,
                                              const float* __restrict__ denA,
                                              const float* __restrict__ logit_in,
                                              const float* __restrict__ p_ls,
                                              float* __restrict__ out) {
    const int b = blockIdx.x;
    const int tid = threadIdx.x;
    const float scale = expf(p_ls[0]);
    __shared__ float a[N_OTH];
    for (int i = tid; i < N_OTH; i += 512) {
        const float nu = numA[(size_t)b * N_OTH + i];
        const float de = denA[(size_t)b * N_OTH + i];
        a[i] = scale * nu / sqrtf(de);
    }
    __syncthreads();
    for (unsigned k = 2; k <= N_OTH; k <<= 1) {
        for (unsigned j = k >> 1; j > 0; j >>= 1) {
#pragma unroll
            for (int s = 0; s < N_OTH / 512; ++s) {
                const unsigned i = tid + s * 512u;
                const unsigned ixj = i ^ j;
                if (ixj > i) {
                    const bool asc = ((i & k) == 0);
                    const float x = a[i], y = a[ixj];
                    if ((x > y) == asc) { a[i] = y; a[ixj] = x; }
                }
            }
            __syncthreads();
        }
    }
    if (tid < 128) {
        const int j = tid;
        float v;
        if (j == b) {
            v = logit_in[b];
        } else {
            const int m = j - (j > b ? 1 : 0);
            v = a[N_OTH - 1 - m];
        }
        out[b * 128 + j] = v;
    }
}

extern "C" void kernel_launch(void* const* d_in, const int* in_sizes, int n_in,
                              void* d_out, int out_size, void* d_ws, size_t ws_size,
                              hipStream_t stream) {
    const float* in_img = (const float*)d_in[0];
    const float* in_txt = (const float*)d_in[1];
    const float* oth    = (const float*)d_in[2];
    const float* W_img  = (const float*)d_in[3];
    const float* W_txt  = (const float*)d_in[4];
    const float* p_ls   = (const float*)d_in[5];
    float* out = (float*)d_out;

    float* ws = (float*)d_ws;
    float* img      = ws;                                  // 65536 floats
    float* logit_in = ws + 65536;                          // 128
    float* numA     = ws + 65536 + 128;                    // 262144
    float* denA     = numA + 262144;                       // 262144
    ushort* wfrag   = (ushort*)(denA + 262144);            // 262144 ushorts (512 KB)

    k_wprep<<<128, 256, 0, stream>>>(W_txt, wfrag);
    k_enc<<<B_SZ, 512, 0, stream>>>(in_img, in_txt, W_img, W_txt, p_ls, img, logit_in);
    k_gemm<<<(B_SZ * N_OTH) / 64, 256, 0, stream>>>(oth, wfrag, img, numA, denA);
    k_topk<<<B_SZ, 512, 0, stream>>>(numA, denA, logit_in, p_ls, out);
}